// Round 2
// baseline (49.105 us; speedup 1.0000x reference)
//
#include <hip/hip_runtime.h>

// YOLO loss: out,label [32768,17,7,7] f32 -> scalar f32.
// Thread-per-cell layout: each thread owns one (batch, cell) and walks the 17
// channels at constant offsets c*49 (folds into the load offset: immediate).
// mask m = label[b,0,cell] is exactly 0.0 or 1.0, so the where() becomes
//   contrib = d0^2*(0.5 + 0.5*m) + m*(5*(loc+size) + class)
// (m=1: d0^2 + 5(loc+size)+class  [prob_loss + weighted terms];
//  m=0: 0.5*d0^2                  [noobj]).

#define BPC    833              // 17*49 floats per batch
#define CELLS  49
#define NCELL  (32768 * CELLS)  // 1,605,632 cells
#define NBLK   2048

__global__ __launch_bounds__(256) void yolo_partial(const float* __restrict__ outp,
                                                    const float* __restrict__ lab,
                                                    float* __restrict__ partial) {
    const int tid    = blockIdx.x * 256 + threadIdx.x;
    const int stride = gridDim.x * 256;
    float acc = 0.0f;

    for (int ci = tid; ci < NCELL; ci += stride) {
        const int b    = ci / CELLS;          // magic-mul, once per 17 elements
        const int cell = ci - b * CELLS;
        const float* __restrict__ lb = lab  + b * BPC + cell;
        const float* __restrict__ ob = outp + b * BPC + cell;

        const float m  = lb[0];               // objectness label == mask
        const float o0 = ob[0];
        const float d0 = m - o0;

        float loc = 0.0f, siz = 0.0f, cls = 0.0f;
#pragma unroll
        for (int c = 1; c <= 2; ++c) {
            const float d = lb[c * CELLS] - ob[c * CELLS];
            loc += d * d;
        }
#pragma unroll
        for (int c = 3; c <= 4; ++c) {
            const float d = sqrtf(lb[c * CELLS]) - sqrtf(ob[c * CELLS]);
            siz += d * d;
        }
#pragma unroll
        for (int c = 5; c <= 16; ++c) {
            const float d = lb[c * CELLS] - ob[c * CELLS];
            cls += d * d;
        }

        acc += d0 * d0 * (0.5f + 0.5f * m) + m * (5.0f * (loc + siz) + cls);
    }

    // wave64 shuffle reduce
#pragma unroll
    for (int off = 32; off > 0; off >>= 1)
        acc += __shfl_down(acc, off, 64);

    __shared__ float wsum[4];
    const int lane = threadIdx.x & 63;
    const int wid  = threadIdx.x >> 6;
    if (lane == 0) wsum[wid] = acc;
    __syncthreads();
    if (threadIdx.x == 0)
        partial[blockIdx.x] = wsum[0] + wsum[1] + wsum[2] + wsum[3];
}

__global__ __launch_bounds__(256) void yolo_final(const float* __restrict__ partial,
                                                  float* __restrict__ outv) {
    float acc = 0.0f;
    for (int i = threadIdx.x; i < NBLK; i += 256) acc += partial[i];
#pragma unroll
    for (int off = 32; off > 0; off >>= 1)
        acc += __shfl_down(acc, off, 64);

    __shared__ float wsum[4];
    const int lane = threadIdx.x & 63;
    const int wid  = threadIdx.x >> 6;
    if (lane == 0) wsum[wid] = acc;
    __syncthreads();
    if (threadIdx.x == 0)
        outv[0] = (wsum[0] + wsum[1] + wsum[2] + wsum[3]) * (1.0f / 1605632.0f);
}

extern "C" void kernel_launch(void* const* d_in, const int* in_sizes, int n_in,
                              void* d_out, int out_size, void* d_ws, size_t ws_size,
                              hipStream_t stream) {
    const float* outp = (const float*)d_in[0];
    const float* lab  = (const float*)d_in[1];
    float* partial    = (float*)d_ws;          // NBLK floats (8 KB)
    float* res        = (float*)d_out;

    yolo_partial<<<NBLK, 256, 0, stream>>>(outp, lab, partial);
    yolo_final<<<1, 256, 0, stream>>>(partial, res);
}

// Round 3
// 44.210 us; speedup vs baseline: 1.1107x; 1.1107x over previous
//
#include <hip/hip_runtime.h>

// YOLO loss: out,label [32768,17,7,7] f32 -> scalar f32.
// Flat float4 streaming over both tensors. Per element at flat index idx:
//   b = idx/833, r = idx%833, c = r/49, cell = r%49, m = label[b*833+cell]
//   contrib = d^2 * (a + b_w*m), with (a,b_w,d):
//     c==0 : (0.5, 0.5, l-o)        [m == l itself; reload is an L1 hit]
//     c 1,2: (0,   5,   l-o)
//     c 3,4: (0,   5,   sqrt(l)-sqrt(o))
//     c>=5 : (0,   1,   l-o)
// r->(a,b_w,cell,sqrt?) comes from an 833-entry LDS LUT (ds_read_b64,
// consecutive lanes -> 8B stride -> free 2-way bank aliasing).
// A float4 crossing a batch boundary (r0>829) wraps into channel 0 of
// batch b+1 (833=17*49), handled by a 2-op wrap that also offsets the
// mask base. One magic-div per float4; zero divs per element.

#define BPC   833
#define CELLS 49
#define NTOT  (32768 * BPC)   // 27,295,744 floats per tensor
#define N4    (NTOT / 4)      // 6,823,936 float4s
#define NBLK  2048

__global__ __launch_bounds__(256) void yolo_partial(const float* __restrict__ outp,
                                                    const float* __restrict__ lab,
                                                    float* __restrict__ partial) {
    __shared__ uint2 lut[BPC];
    for (int r = threadIdx.x; r < BPC; r += 256) {
        const int c    = r / CELLS;
        const int cell = r - c * CELLS;
        unsigned wa, wb;                       // bf16 halves (exact values)
        if (c == 0)      { wa = 0x3F00u; wb = 0x3F00u; }   // a=0.5, b=0.5
        else if (c <= 4) { wa = 0x0000u; wb = 0x40A0u; }   // a=0,   b=5
        else             { wa = 0x0000u; wb = 0x3F80u; }   // a=0,   b=1
        const bool sq = (c == 3) || (c == 4);
        lut[r].x = (wa << 16) | wb;
        lut[r].y = (unsigned)cell | (sq ? 0x100u : 0u);
    }
    __syncthreads();

    const int tid    = blockIdx.x * 256 + threadIdx.x;
    const int stride = gridDim.x * 256;
    float acc = 0.0f;

    for (int i4 = tid; i4 < N4; i4 += stride) {
        const float4 o4 = reinterpret_cast<const float4*>(outp)[i4];
        const float4 l4 = reinterpret_cast<const float4*>(lab)[i4];
        const float ov[4] = {o4.x, o4.y, o4.z, o4.w};
        const float lv[4] = {l4.x, l4.y, l4.z, l4.w};

        const unsigned idx   = (unsigned)i4 * 4u;
        const unsigned b     = idx / 833u;        // one magic-div per float4
        const unsigned bbase = b * 833u;          // folded: idx - r0
        const unsigned r0    = idx - bbase;

#pragma unroll
        for (int j = 0; j < 4; ++j) {
            const unsigned rj   = r0 + j;
            const unsigned wrap = (rj >= 833u) ? 833u : 0u;  // crossing -> ch0 of b+1
            const unsigned r    = rj - wrap;
            const uint2 e = lut[r];
            const float  a  = __uint_as_float(e.x & 0xFFFF0000u);
            const float  bw = __uint_as_float(e.x << 16);
            const unsigned cell = e.y & 0xFFu;
            const float m  = lab[bbase + wrap + cell];       // L1/L2-hot
            const float o1 = ov[j], l1 = lv[j];
            const float dl = l1 - o1;
            const float dq = sqrtf(l1) - sqrtf(o1);          // inputs > 0
            const float d  = (e.y >= 0x100u) ? dq : dl;
            acc += d * d * fmaf(bw, m, a);
        }
    }

    // wave64 shuffle reduce
#pragma unroll
    for (int off = 32; off > 0; off >>= 1)
        acc += __shfl_down(acc, off, 64);

    __shared__ float wsum[4];
    const int lane = threadIdx.x & 63;
    const int wid  = threadIdx.x >> 6;
    if (lane == 0) wsum[wid] = acc;
    __syncthreads();
    if (threadIdx.x == 0)
        partial[blockIdx.x] = wsum[0] + wsum[1] + wsum[2] + wsum[3];
}

__global__ __launch_bounds__(256) void yolo_final(const float* __restrict__ partial,
                                                  float* __restrict__ outv) {
    float acc = 0.0f;
    for (int i = threadIdx.x; i < NBLK; i += 256) acc += partial[i];
#pragma unroll
    for (int off = 32; off > 0; off >>= 1)
        acc += __shfl_down(acc, off, 64);

    __shared__ float wsum[4];
    const int lane = threadIdx.x & 63;
    const int wid  = threadIdx.x >> 6;
    if (lane == 0) wsum[wid] = acc;
    __syncthreads();
    if (threadIdx.x == 0)
        outv[0] = (wsum[0] + wsum[1] + wsum[2] + wsum[3]) * (1.0f / 1605632.0f);
}

extern "C" void kernel_launch(void* const* d_in, const int* in_sizes, int n_in,
                              void* d_out, int out_size, void* d_ws, size_t ws_size,
                              hipStream_t stream) {
    const float* outp = (const float*)d_in[0];
    const float* lab  = (const float*)d_in[1];
    float* partial    = (float*)d_ws;          // NBLK floats (8 KB)
    float* res        = (float*)d_out;

    yolo_partial<<<NBLK, 256, 0, stream>>>(outp, lab, partial);
    yolo_final<<<1, 256, 0, stream>>>(partial, res);
}